// Round 3
// baseline (575.802 us; speedup 1.0000x reference)
//
#include <hip/hip_runtime.h>
#include <stdint.h>

#define SEQS 64
#define QL 4
#define KL 2048
#define NH 32
#define KVH 4
#define GRP 8
#define DN 128
#define DR 64
#define BS 16

typedef __attribute__((ext_vector_type(4))) float f32x4;
typedef __attribute__((ext_vector_type(8))) short s16x8;
typedef __attribute__((ext_vector_type(4))) short s16x4;

#define VT_STRIDE 40   // shorts per V^T dim-row: 32 tokens + 8 pad (bank decorrelation)
#define P_STRIDE  40   // shorts per P qrow
#define Q_STRIDE  202  // shorts per Q row: 192 dims + 10 pad -> dword stride 101 (odd, conflict-free)

// LDS map (bytes):
//   [0, 12928)        Qs : 32 qcols x 202 shorts (bf16, shared by all waves)
//   [12928, 94848)    Vt : 8 waves x 128 dims x 40 shorts
//   [94848, 115328)   Pl : 8 waves x 32 qcols x 40 shorts
// combine phase reuses [0, 66560) as 4 fp32 slots of 4160 floats each
#define QS_BYTES (32 * Q_STRIDE * 2)
#define VT_BYTES (8 * DN * VT_STRIDE * 2)
#define PL_BYTES (8 * 32 * P_STRIDE * 2)
#define SMEM_BYTES (QS_BYTES + VT_BYTES + PL_BYTES)

__device__ __forceinline__ short f2bf(float f) {
    union { float f; uint32_t u; } v; v.f = f;
    uint32_t r = (v.u + 0x7FFFu + ((v.u >> 16) & 1u)) >> 16;  // RNE
    return (short)r;
}

__device__ __forceinline__ s16x8 cvt8(f32x4 a, f32x4 b) {
    s16x8 r;
    r[0] = f2bf(a[0]); r[1] = f2bf(a[1]); r[2] = f2bf(a[2]); r[3] = f2bf(a[3]);
    r[4] = f2bf(b[0]); r[5] = f2bf(b[1]); r[6] = f2bf(b[2]); r[7] = f2bf(b[3]);
    return r;
}

// grid: 256 blocks = (seq, kv_head); 512 threads = 8 waves; wave w owns tokens [w*256, w*256+256)
// waves_per_eu(2) pins the allocator at a 256-VGPR budget (round-1's launch_bounds(512,2) was
// honored as a 128-VGPR cap -> 200 MB scratch spill, visible in WRITE_SIZE).
// Prefetch: each tile's f32 regs are cvt'd to bf16 on arrival and immediately reissued for
// tile t+2, so 24 loads stay in flight through compute with only ~60 live prefetch VGPRs.
__global__ __attribute__((amdgpu_flat_work_group_size(512, 512), amdgpu_waves_per_eu(2)))
void mla_decode(
    const float* __restrict__ qn, const float* __restrict__ qr,
    const float* __restrict__ kn, const float* __restrict__ kr,
    const int* __restrict__ bt, float* __restrict__ out)
{
    __shared__ __align__(16) char smem[SMEM_BYTES];

    const int tid = threadIdx.x;
    const int w   = tid >> 6;          // 0..7
    const int l   = tid & 63;
    const int s   = blockIdx.x >> 2;
    const int h   = blockIdx.x & 3;
    const int l15 = l & 15;
    const int l4  = l >> 4;

    short* Qs = (short*)smem;
    short* Vt = (short*)(smem + QS_BYTES) + w * (DN * VT_STRIDE);
    short* Pl = (short*)(smem + QS_BYTES + VT_BYTES) + w * (32 * P_STRIDE);

    const float scale = 0.07216878364870322f;  // 1/sqrt(192)

    const int btbase = s * (KL / BS) + w * 16;
    // 16 block ids for this wave, lane-indexed on l15 (upper lane groups replicate)
    const int btreg = bt[btbase + l15];

    // issue the 12 float4 loads (one 16-token kv-block: 128 nope + 64 rope dims) for block id blkv
    auto loadK = [&](int blkv, f32x4* dst) {
        int blk = __builtin_amdgcn_readfirstlane(blkv);   // scalar base -> SALU addressing
        const float* knb = kn + ((size_t)(blk*BS + l15)*KVH + h) * DN + l4*8;
        const float* krb = kr + ((size_t)(blk*BS + l15)*KVH + h) * DR + l4*8;
        #pragma unroll
        for (int ks = 0; ks < 4; ++ks) {
            dst[2*ks]   = *(const f32x4*)(knb + 32*ks);
            dst[2*ks+1] = *(const f32x4*)(knb + 32*ks + 4);
        }
        #pragma unroll
        for (int ks = 0; ks < 2; ++ks) {
            dst[8+2*ks]   = *(const f32x4*)(krb + 32*ks);
            dst[8+2*ks+1] = *(const f32x4*)(krb + 32*ks + 4);
        }
    };

    f32x4 buf0[12], buf1[12];
    loadK(__shfl(btreg, 0, 64), buf0);   // start HBM before Q staging

    // ---- stage Q -> LDS (bf16): wave w covers qcols [4w, 4w+4); lanes 0..47 cvt 4 floats each
    if (l < 48) {
        #pragma unroll
        for (int i = 0; i < 4; ++i) {
            int qcol = w * 4 + i;
            int qpos = qcol >> 3, g = qcol & 7;
            const float* src = (l < 32)
                ? qn + ((size_t)((s*QL + qpos)*NH + h*GRP + g)) * DN + l*4
                : qr + ((size_t)((s*QL + qpos)*NH + h*GRP + g)) * DR + (l-32)*4;
            f32x4 v = *(const f32x4*)src;
            s16x4 o;
            o[0] = f2bf(v[0]); o[1] = f2bf(v[1]); o[2] = f2bf(v[2]); o[3] = f2bf(v[3]);
            *(s16x4*)(Qs + qcol*Q_STRIDE + l*4) = o;
        }
    }
    loadK(__shfl(btreg, 1, 64), buf1);
    __syncthreads();

    f32x4 of[8][2];                    // O^T accum: row dim=16mt+(l>>4)*4+r, col qcol=(l&15)+16nt
    #pragma unroll
    for (int mt = 0; mt < 8; ++mt)
        #pragma unroll
        for (int nt = 0; nt < 2; ++nt) of[mt][nt] = f32x4{0.f, 0.f, 0.f, 0.f};
    float m2[2] = {-INFINITY, -INFINITY};
    float l2[2] = {0.f, 0.f};

    #pragma unroll 1
    for (int c = 0; c < 8; ++c) {   // 8 chunks x 32 tokens per wave
        // ---- drain tile 2c, reissue tile 2c+2; drain tile 2c+1, reissue tile 2c+3.
        // bf16 conversion frees the f32 buffer immediately so the reissued loads
        // ride through the whole compute phase (~24 loads in flight/wave).
        s16x8 af0[6], af1[6];
        #pragma unroll
        for (int ks = 0; ks < 6; ++ks) af0[ks] = cvt8(buf0[2*ks], buf0[2*ks+1]);
        if (c < 7) loadK(__shfl(btreg, 2*c + 2, 64), buf0);
        #pragma unroll
        for (int ks = 0; ks < 6; ++ks) af1[ks] = cvt8(buf1[2*ks], buf1[2*ks+1]);
        if (c < 7) loadK(__shfl(btreg, 2*c + 3, 64), buf1);

        // ---- Q fragments, once per chunk (dword stride 101 -> conflict-free b128)
        s16x8 qfl[6][2];
        #pragma unroll
        for (int ks = 0; ks < 6; ++ks) {
            qfl[ks][0] = *(const s16x8*)(Qs + l15*Q_STRIDE + 32*ks + l4*8);
            qfl[ks][1] = *(const s16x8*)(Qs + (l15+16)*Q_STRIDE + 32*ks + l4*8);
        }

        // ---- stage V^T (nope dims only); same-wave lgkm ordering, no barrier
        #pragma unroll
        for (int ks = 0; ks < 4; ++ks) {
            int dbase = l4*8 + 32*ks;
            #pragma unroll
            for (int j = 0; j < 8; ++j) {
                Vt[(dbase + j) * VT_STRIDE + l15]      = af0[ks][j];
                Vt[(dbase + j) * VT_STRIDE + 16 + l15] = af1[ks][j];
            }
        }

        // ---- S^T = K * Q^T  (A = K tile: m=token, B = Q: n=qcol)
        f32x4 sf[2][2];
        #pragma unroll
        for (int mt = 0; mt < 2; ++mt)
            #pragma unroll
            for (int nt = 0; nt < 2; ++nt) sf[mt][nt] = f32x4{0.f, 0.f, 0.f, 0.f};
        #pragma unroll
        for (int ks = 0; ks < 6; ++ks) {
            sf[0][0] = __builtin_amdgcn_mfma_f32_16x16x32_bf16(af0[ks], qfl[ks][0], sf[0][0], 0, 0, 0);
            sf[0][1] = __builtin_amdgcn_mfma_f32_16x16x32_bf16(af0[ks], qfl[ks][1], sf[0][1], 0, 0, 0);
            sf[1][0] = __builtin_amdgcn_mfma_f32_16x16x32_bf16(af1[ks], qfl[ks][0], sf[1][0], 0, 0, 0);
            sf[1][1] = __builtin_amdgcn_mfma_f32_16x16x32_bf16(af1[ks], qfl[ks][1], sf[1][1], 0, 0, 0);
        }

        // ---- online softmax over this chunk's 32 tokens
        float cmax[2] = {-INFINITY, -INFINITY};
        #pragma unroll
        for (int mt = 0; mt < 2; ++mt)
            #pragma unroll
            for (int nt = 0; nt < 2; ++nt)
                #pragma unroll
                for (int r = 0; r < 4; ++r) cmax[nt] = fmaxf(cmax[nt], sf[mt][nt][r]);
        #pragma unroll
        for (int nt = 0; nt < 2; ++nt) {
            cmax[nt] = fmaxf(cmax[nt], __shfl_xor(cmax[nt], 16, 64));
            cmax[nt] = fmaxf(cmax[nt], __shfl_xor(cmax[nt], 32, 64));
        }
        float alpha[2], psum[2];
        #pragma unroll
        for (int nt = 0; nt < 2; ++nt) {
            float mn = fmaxf(m2[nt], cmax[nt] * scale);
            alpha[nt] = __expf(m2[nt] - mn);
            m2[nt] = mn;
            psum[nt] = 0.f;
        }
        float p[2][2][4];
        #pragma unroll
        for (int mt = 0; mt < 2; ++mt)
            #pragma unroll
            for (int nt = 0; nt < 2; ++nt)
                #pragma unroll
                for (int r = 0; r < 4; ++r) {
                    float e = __expf(sf[mt][nt][r] * scale - m2[nt]);
                    p[mt][nt][r] = e; psum[nt] += e;
                }
        #pragma unroll
        for (int nt = 0; nt < 2; ++nt) {
            psum[nt] += __shfl_xor(psum[nt], 16, 64);
            psum[nt] += __shfl_xor(psum[nt], 32, 64);
            l2[nt] = l2[nt] * alpha[nt] + psum[nt];
        }
        #pragma unroll
        for (int mt = 0; mt < 8; ++mt)
            #pragma unroll
            for (int nt = 0; nt < 2; ++nt) {
                of[mt][nt][0] *= alpha[nt]; of[mt][nt][1] *= alpha[nt];
                of[mt][nt][2] *= alpha[nt]; of[mt][nt][3] *= alpha[nt];
            }

        // ---- P round-trip: C-layout -> b64 write; B-frag b128 read
        #pragma unroll
        for (int mt = 0; mt < 2; ++mt)
            #pragma unroll
            for (int nt = 0; nt < 2; ++nt) {
                unsigned lo = (unsigned short)f2bf(p[mt][nt][0]) | ((unsigned)(unsigned short)f2bf(p[mt][nt][1]) << 16);
                unsigned hi = (unsigned short)f2bf(p[mt][nt][2]) | ((unsigned)(unsigned short)f2bf(p[mt][nt][3]) << 16);
                unsigned long long v = (unsigned long long)lo | ((unsigned long long)hi << 32);
                *(unsigned long long*)(Pl + (l15 + 16*nt) * P_STRIDE + 16*mt + l4*4) = v;
            }
        s16x8 pf[2];
        #pragma unroll
        for (int nt = 0; nt < 2; ++nt)
            pf[nt] = *(const s16x8*)(Pl + (l15 + 16*nt) * P_STRIDE + l4*8);

        // ---- O^T += V^T * P^T
        #pragma unroll
        for (int mt = 0; mt < 8; ++mt) {
            s16x8 vf = *(const s16x8*)(Vt + (l15 + 16*mt) * VT_STRIDE + l4*8);
            of[mt][0] = __builtin_amdgcn_mfma_f32_16x16x32_bf16(vf, pf[0], of[mt][0], 0, 0, 0);
            of[mt][1] = __builtin_amdgcn_mfma_f32_16x16x32_bf16(vf, pf[1], of[mt][1], 0, 0, 0);
        }
    }

    // ---- cross-wave flash combine (3-level tree, 4 fp32 LDS slots, reuses main-loop LDS)
    auto dump = [&](int slot) {
        float* sp = (float*)smem + slot * 4160;
        #pragma unroll
        for (int mt = 0; mt < 8; ++mt)
            #pragma unroll
            for (int nt = 0; nt < 2; ++nt)
                #pragma unroll
                for (int r = 0; r < 4; ++r)
                    sp[(16*mt + l4*4 + r) * 32 + l15 + 16*nt] = of[mt][nt][r];
        if (l4 == 0) {
            sp[4096 + l15]      = m2[0]; sp[4096 + 16 + l15] = m2[1];
            sp[4128 + l15]      = l2[0]; sp[4128 + 16 + l15] = l2[1];
        }
    };
    auto merge = [&](int slot) {
        float* sp = (float*)smem + slot * 4160;
        float as[2], ao[2];
        #pragma unroll
        for (int nt = 0; nt < 2; ++nt) {
            int qcol = l15 + 16*nt;
            float mo = sp[4096 + qcol];
            float lo = sp[4128 + qcol];
            float mn = fmaxf(m2[nt], mo);
            as[nt] = __expf(m2[nt] - mn);
            ao[nt] = __expf(mo - mn);
            l2[nt] = l2[nt] * as[nt] + lo * ao[nt];
            m2[nt] = mn;
        }
        #pragma unroll
        for (int mt = 0; mt < 8; ++mt)
            #pragma unroll
            for (int nt = 0; nt < 2; ++nt)
                #pragma unroll
                for (int r = 0; r < 4; ++r)
                    of[mt][nt][r] = of[mt][nt][r] * as[nt]
                                  + sp[(16*mt + l4*4 + r) * 32 + l15 + 16*nt] * ao[nt];
    };

    __syncthreads();
    if (w & 1) dump(w >> 1);                 // 1,3,5,7 -> slots 0..3
    __syncthreads();
    if (!(w & 1)) merge(w >> 1);             // 0,2,4,6 merge partners
    __syncthreads();
    if (w == 2 || w == 6) dump(w >> 2);      // 2,6 -> slots 0,1
    __syncthreads();
    if (w == 0 || w == 4) merge(w >> 2);
    __syncthreads();
    if (w == 4) dump(0);
    __syncthreads();
    if (w == 0) {
        merge(0);
        float inv[2] = {1.f / l2[0], 1.f / l2[1]};
        #pragma unroll
        for (int nt = 0; nt < 2; ++nt) {
            int qcol = l15 + 16*nt;
            int qpos = qcol >> 3, g = qcol & 7;
            float* ob = out + ((size_t)((s*QL + qpos)*NH + h*GRP + g)) * DN;
            #pragma unroll
            for (int mt = 0; mt < 8; ++mt) {
                f32x4 v;
                v[0] = of[mt][nt][0] * inv[nt]; v[1] = of[mt][nt][1] * inv[nt];
                v[2] = of[mt][nt][2] * inv[nt]; v[3] = of[mt][nt][3] * inv[nt];
                *(f32x4*)(ob + 16*mt + l4*4) = v;
            }
        }
    }
}

extern "C" void kernel_launch(void* const* d_in, const int* in_sizes, int n_in,
                              void* d_out, int out_size, void* d_ws, size_t ws_size,
                              hipStream_t stream) {
    (void)in_sizes; (void)n_in; (void)out_size; (void)d_ws; (void)ws_size;
    const float* qn = (const float*)d_in[0];
    const float* qr = (const float*)d_in[1];
    const float* kn = (const float*)d_in[2];
    const float* kr = (const float*)d_in[3];
    const int*   bt = (const int*)d_in[4];
    float* out = (float*)d_out;
    mla_decode<<<SEQS * KVH, 512, 0, stream>>>(qn, qr, kn, kr, bt, out);
}

// Round 4
// 430.326 us; speedup vs baseline: 1.3381x; 1.3381x over previous
//
#include <hip/hip_runtime.h>
#include <stdint.h>

#define SEQS 64
#define QL 4
#define KL 2048
#define NH 32
#define KVH 4
#define GRP 8
#define DN 128
#define DR 64
#define BS 16

typedef __attribute__((ext_vector_type(4))) float f32x4;
typedef __attribute__((ext_vector_type(8))) short s16x8;

#define VT_STRIDE 40   // shorts per V^T dim-row: 32 tokens + 8 pad (bank decorrelation)
#define P_STRIDE  40   // shorts per P qrow

__device__ __forceinline__ short f2bf(float f) {
    union { float f; uint32_t u; } v; v.f = f;
    uint32_t r = (v.u + 0x7FFFu + ((v.u >> 16) & 1u)) >> 16;  // RNE
    return (short)r;
}

__device__ __forceinline__ s16x8 cvt8(f32x4 a, f32x4 b) {
    s16x8 r;
    r[0] = f2bf(a[0]); r[1] = f2bf(a[1]); r[2] = f2bf(a[2]); r[3] = f2bf(a[3]);
    r[4] = f2bf(b[0]); r[5] = f2bf(b[1]); r[6] = f2bf(b[2]); r[7] = f2bf(b[3]);
    return r;
}

// grid: 256 blocks = (seq, kv_head) via XCD-grouped remap; 256 threads = 4 waves;
// wave w owns tokens [w*512, w*512+512).
// Remap puts all 4 h-blocks of a seq on ONE XCD (XCD = blockIdx%8): their interleaved
// 768B-per-3KB head slices merge into full DRAM rows (row-locality fix for the 2.65 TB/s cap).
// Prefetch: quad-buffered (4 tiles = 48 float4 loads in flight) with chunk-pair unroll,
// doubling outstanding bytes vs the 2-tile version (Little's law: BW = in-flight/latency).
// 1 wave/SIMD keeps the full 512-reg unified budget: NO occupancy attr (rounds 1/3 showed
// any waves_per_eu/launch_bounds(,2) pin -> 128-VGPR cap -> 200-380 MB scratch spill).
__global__ __launch_bounds__(256, 1) void mla_decode(
    const float* __restrict__ qn, const float* __restrict__ qr,
    const float* __restrict__ kn, const float* __restrict__ kr,
    const int* __restrict__ bt, float* __restrict__ out)
{
    // LDS: [0,40960): V^T per wave (128 dims x 40 shorts); [40960,51200): P per wave (32 x 40 shorts)
    // combine phase reuses [0, 33280) as two fp32 slots of 4160 floats each
    __shared__ __align__(16) char smem[51200];

    const int tid = threadIdx.x;
    const int w   = tid >> 6;
    const int l   = tid & 63;
    const int b   = blockIdx.x;
    const int s   = (b & 7) | ((b >> 5) << 3);   // bijective: all 4 h of seq s on XCD s%8
    const int h   = (b >> 3) & 3;
    const int l15 = l & 15;
    const int l4  = l >> 4;

    short* Vt = (short*)smem + w * (DN * VT_STRIDE);
    short* Pl = (short*)(smem + 4 * DN * VT_STRIDE * 2) + w * (32 * P_STRIDE);

    // ---- Q fragments (B-layout, resident all kernel): qf[ks][nt]
    s16x8 qf[6][2];
    #pragma unroll
    for (int nt = 0; nt < 2; ++nt) {
        int qcol = l15 + 16 * nt;
        int qpos = qcol >> 3, g = qcol & 7;
        const float* qnb = qn + ((size_t)((s*QL + qpos)*NH + h*GRP + g)) * DN + l4*8;
        const float* qrb = qr + ((size_t)((s*QL + qpos)*NH + h*GRP + g)) * DR + l4*8;
        #pragma unroll
        for (int ks = 0; ks < 4; ++ks) {
            f32x4 a = *(const f32x4*)(qnb + 32*ks);
            f32x4 bq = *(const f32x4*)(qnb + 32*ks + 4);
            qf[ks][nt] = cvt8(a, bq);
        }
        #pragma unroll
        for (int ks = 0; ks < 2; ++ks) {
            f32x4 a = *(const f32x4*)(qrb + 32*ks);
            f32x4 bq = *(const f32x4*)(qrb + 32*ks + 4);
            qf[4+ks][nt] = cvt8(a, bq);
        }
    }

    const float scale = 0.07216878364870322f;  // 1/sqrt(192)

    f32x4 of[8][2];                    // O^T accum: row dim=16mt+(l>>4)*4+r, col qcol=(l&15)+16nt
    #pragma unroll
    for (int mt = 0; mt < 8; ++mt)
        #pragma unroll
        for (int nt = 0; nt < 2; ++nt) of[mt][nt] = f32x4{0.f, 0.f, 0.f, 0.f};
    float m2[2] = {-INFINITY, -INFINITY};
    float l2[2] = {0.f, 0.f};

    const int btbase = s * (KL / BS) + w * 32;
    // all 32 block ids for this wave, lane-indexed (lanes 32-63 duplicate): kills per-chunk bt stall
    const int btreg = bt[btbase + (l & 31)];

    // issue the 12 float4 loads (one 16-token kv-block: 128 nope + 64 rope dims) for block id blkv
    auto loadK = [&](int blkv, f32x4* dst) {
        int blk = __builtin_amdgcn_readfirstlane(blkv);   // scalar base -> SALU addressing
        const float* knb = kn + ((size_t)(blk*BS + l15)*KVH + h) * DN + l4*8;
        const float* krb = kr + ((size_t)(blk*BS + l15)*KVH + h) * DR + l4*8;
        #pragma unroll
        for (int ks = 0; ks < 4; ++ks) {
            dst[2*ks]   = *(const f32x4*)(knb + 32*ks);
            dst[2*ks+1] = *(const f32x4*)(knb + 32*ks + 4);
        }
        #pragma unroll
        for (int ks = 0; ks < 2; ++ks) {
            dst[8+2*ks]   = *(const f32x4*)(krb + 32*ks);
            dst[8+2*ks+1] = *(const f32x4*)(krb + 32*ks + 4);
        }
    };

    f32x4 buf0[12], buf1[12], buf2[12], buf3[12];
    loadK(__shfl(btreg, 0, 64), buf0);
    loadK(__shfl(btreg, 1, 64), buf1);
    loadK(__shfl(btreg, 2, 64), buf2);
    loadK(__shfl(btreg, 3, 64), buf3);

    // one chunk = 32 tokens = tiles t, t+1 in buffers A, B; reloads tiles t+4, t+5 into A, B
    auto chunk = [&](f32x4* A, f32x4* B, int t, bool pf) {
        f32x4 sf[2][2];
        #pragma unroll
        for (int mt = 0; mt < 2; ++mt)
            #pragma unroll
            for (int nt = 0; nt < 2; ++nt) sf[mt][nt] = f32x4{0.f, 0.f, 0.f, 0.f};

        auto qkstep = [&](const f32x4* ld, int mt) {
            s16x8 af[6];
            #pragma unroll
            for (int ks = 0; ks < 6; ++ks) af[ks] = cvt8(ld[2*ks], ld[2*ks+1]);
            // stage V^T (nope dims only); same-wave lgkm ordering, no barrier
            #pragma unroll
            for (int ks = 0; ks < 4; ++ks) {
                int dbase = l4*8 + 32*ks;
                #pragma unroll
                for (int j = 0; j < 8; ++j)
                    Vt[(dbase + j) * VT_STRIDE + 16*mt + l15] = af[ks][j];
            }
            // S^T = K * Q^T  (A = K tile: m=token, B = Q: n=qcol)
            #pragma unroll
            for (int ks = 0; ks < 6; ++ks) {
                sf[mt][0] = __builtin_amdgcn_mfma_f32_16x16x32_bf16(af[ks], qf[ks][0], sf[mt][0], 0, 0, 0);
                sf[mt][1] = __builtin_amdgcn_mfma_f32_16x16x32_bf16(af[ks], qf[ks][1], sf[mt][1], 0, 0, 0);
            }
        };

        qkstep(A, 0);
        if (pf) loadK(__shfl(btreg, t + 4, 64), A);
        qkstep(B, 1);
        if (pf) loadK(__shfl(btreg, t + 5, 64), B);

        // ---- online softmax over this chunk's 32 tokens
        float cmax[2] = {-INFINITY, -INFINITY};
        #pragma unroll
        for (int mt = 0; mt < 2; ++mt)
            #pragma unroll
            for (int nt = 0; nt < 2; ++nt)
                #pragma unroll
                for (int r = 0; r < 4; ++r) cmax[nt] = fmaxf(cmax[nt], sf[mt][nt][r]);
        #pragma unroll
        for (int nt = 0; nt < 2; ++nt) {
            cmax[nt] = fmaxf(cmax[nt], __shfl_xor(cmax[nt], 16, 64));
            cmax[nt] = fmaxf(cmax[nt], __shfl_xor(cmax[nt], 32, 64));
        }
        float alpha[2], psum[2];
        #pragma unroll
        for (int nt = 0; nt < 2; ++nt) {
            float mn = fmaxf(m2[nt], cmax[nt] * scale);
            alpha[nt] = __expf(m2[nt] - mn);
            m2[nt] = mn;
            psum[nt] = 0.f;
        }
        float p[2][2][4];
        #pragma unroll
        for (int mt = 0; mt < 2; ++mt)
            #pragma unroll
            for (int nt = 0; nt < 2; ++nt)
                #pragma unroll
                for (int r = 0; r < 4; ++r) {
                    float e = __expf(sf[mt][nt][r] * scale - m2[nt]);
                    p[mt][nt][r] = e; psum[nt] += e;
                }
        #pragma unroll
        for (int nt = 0; nt < 2; ++nt) {
            psum[nt] += __shfl_xor(psum[nt], 16, 64);
            psum[nt] += __shfl_xor(psum[nt], 32, 64);
            l2[nt] = l2[nt] * alpha[nt] + psum[nt];
        }
        #pragma unroll
        for (int mt = 0; mt < 8; ++mt)
            #pragma unroll
            for (int nt = 0; nt < 2; ++nt) {
                of[mt][nt][0] *= alpha[nt]; of[mt][nt][1] *= alpha[nt];
                of[mt][nt][2] *= alpha[nt]; of[mt][nt][3] *= alpha[nt];
            }

        // ---- P round-trip: C-layout -> b64 write; B-frag b128 read
        #pragma unroll
        for (int mt = 0; mt < 2; ++mt)
            #pragma unroll
            for (int nt = 0; nt < 2; ++nt) {
                unsigned lo = (unsigned short)f2bf(p[mt][nt][0]) | ((unsigned)(unsigned short)f2bf(p[mt][nt][1]) << 16);
                unsigned hi = (unsigned short)f2bf(p[mt][nt][2]) | ((unsigned)(unsigned short)f2bf(p[mt][nt][3]) << 16);
                unsigned long long v = (unsigned long long)lo | ((unsigned long long)hi << 32);
                *(unsigned long long*)(Pl + (l15 + 16*nt) * P_STRIDE + 16*mt + l4*4) = v;
            }
        s16x8 pf2[2];
        #pragma unroll
        for (int nt = 0; nt < 2; ++nt)
            pf2[nt] = *(const s16x8*)(Pl + (l15 + 16*nt) * P_STRIDE + l4*8);

        // ---- O^T += V^T * P^T
        #pragma unroll
        for (int mt = 0; mt < 8; ++mt) {
            s16x8 vf = *(const s16x8*)(Vt + (l15 + 16*mt) * VT_STRIDE + l4*8);
            of[mt][0] = __builtin_amdgcn_mfma_f32_16x16x32_bf16(vf, pf2[0], of[mt][0], 0, 0, 0);
            of[mt][1] = __builtin_amdgcn_mfma_f32_16x16x32_bf16(vf, pf2[1], of[mt][1], 0, 0, 0);
        }
    };

    #pragma unroll 1
    for (int cp = 0; cp < 8; ++cp) {   // 8 chunk-pairs x 64 tokens per wave
        chunk(buf0, buf1, 4*cp,     cp < 7);
        chunk(buf2, buf3, 4*cp + 2, cp < 7);
    }

    // ---- cross-wave flash combine (tree, 2 fp32 LDS slots, reuses main-loop LDS)
    auto dump = [&](int slot) {
        float* sp = (float*)smem + slot * 4160;
        #pragma unroll
        for (int mt = 0; mt < 8; ++mt)
            #pragma unroll
            for (int nt = 0; nt < 2; ++nt)
                #pragma unroll
                for (int r = 0; r < 4; ++r)
                    sp[(16*mt + l4*4 + r) * 32 + l15 + 16*nt] = of[mt][nt][r];
        if (l4 == 0) {
            sp[4096 + l15]      = m2[0]; sp[4096 + 16 + l15] = m2[1];
            sp[4128 + l15]      = l2[0]; sp[4128 + 16 + l15] = l2[1];
        }
    };
    auto merge = [&](int slot) {
        float* sp = (float*)smem + slot * 4160;
        float as[2], ao[2];
        #pragma unroll
        for (int nt = 0; nt < 2; ++nt) {
            int qcol = l15 + 16*nt;
            float mo = sp[4096 + qcol];
            float lo = sp[4128 + qcol];
            float mn = fmaxf(m2[nt], mo);
            as[nt] = __expf(m2[nt] - mn);
            ao[nt] = __expf(mo - mn);
            l2[nt] = l2[nt] * as[nt] + lo * ao[nt];
            m2[nt] = mn;
        }
        #pragma unroll
        for (int mt = 0; mt < 8; ++mt)
            #pragma unroll
            for (int nt = 0; nt < 2; ++nt)
                #pragma unroll
                for (int r = 0; r < 4; ++r)
                    of[mt][nt][r] = of[mt][nt][r] * as[nt]
                                  + sp[(16*mt + l4*4 + r) * 32 + l15 + 16*nt] * ao[nt];
    };

    __syncthreads();
    if (w & 1) dump(w >> 1);          // waves 1,3 -> slots 0,1
    __syncthreads();
    if (!(w & 1)) merge(w >> 1);      // waves 0,2 merge partners
    __syncthreads();
    if (w == 2) dump(0);
    __syncthreads();
    if (w == 0) {
        merge(0);
        float inv[2] = {1.f / l2[0], 1.f / l2[1]};
        #pragma unroll
        for (int nt = 0; nt < 2; ++nt) {
            int qcol = l15 + 16*nt;
            int qpos = qcol >> 3, g = qcol & 7;
            float* ob = out + ((size_t)((s*QL + qpos)*NH + h*GRP + g)) * DN;
            #pragma unroll
            for (int mt = 0; mt < 8; ++mt) {
                f32x4 v;
                v[0] = of[mt][nt][0] * inv[nt]; v[1] = of[mt][nt][1] * inv[nt];
                v[2] = of[mt][nt][2] * inv[nt]; v[3] = of[mt][nt][3] * inv[nt];
                *(f32x4*)(ob + 16*mt + l4*4) = v;
            }
        }
    }
}

extern "C" void kernel_launch(void* const* d_in, const int* in_sizes, int n_in,
                              void* d_out, int out_size, void* d_ws, size_t ws_size,
                              hipStream_t stream) {
    (void)in_sizes; (void)n_in; (void)out_size; (void)d_ws; (void)ws_size;
    const float* qn = (const float*)d_in[0];
    const float* qr = (const float*)d_in[1];
    const float* kn = (const float*)d_in[2];
    const float* kr = (const float*)d_in[3];
    const int*   bt = (const int*)d_in[4];
    float* out = (float*)d_out;
    mla_decode<<<SEQS * KVH, 256, 0, stream>>>(qn, qr, kn, kr, bt, out);
}

// Round 5
// 428.477 us; speedup vs baseline: 1.3438x; 1.0043x over previous
//
#include <hip/hip_runtime.h>
#include <stdint.h>

#define SEQS 64
#define QL 4
#define KL 2048
#define NH 32
#define KVH 4
#define GRP 8
#define DN 128
#define DR 64
#define BS 16

typedef __attribute__((ext_vector_type(4))) float f32x4;
typedef __attribute__((ext_vector_type(8))) short s16x8;

#define VT_STRIDE 40   // shorts per V^T dim-row: 32 tokens + 8 pad (bank decorrelation)
#define P_STRIDE  40   // shorts per P qrow

__device__ __forceinline__ short f2bf(float f) {
    union { float f; uint32_t u; } v; v.f = f;
    uint32_t r = (v.u + 0x7FFFu + ((v.u >> 16) & 1u)) >> 16;  // RNE
    return (short)r;
}

__device__ __forceinline__ s16x8 cvt8(f32x4 a, f32x4 b) {
    s16x8 r;
    r[0] = f2bf(a[0]); r[1] = f2bf(a[1]); r[2] = f2bf(a[2]); r[3] = f2bf(a[3]);
    r[4] = f2bf(b[0]); r[5] = f2bf(b[1]); r[6] = f2bf(b[2]); r[7] = f2bf(b[3]);
    return r;
}

// grid: 256 blocks = (seq, kv_head) via XCD-grouped remap; 256 threads = 4 waves;
// wave w owns the 32 kv-blocks of token range [w*512, w*512+512) -- processed in
// SORTED kv-block-id order (online softmax is token-order invariant). All waves
// machine-wide sweep the kv-cache address space ascending & concurrently:
//  - cross-seq repeated kv-blocks (~37% of refs) get tiny reuse distance -> L2/L3 hits
//  - the 4 h-blocks of a seq (same bt row, same sorted order, same XCD via remap)
//    touch each 2KB token line's 4 complementary slices back-to-back
// Quad-buffered register prefetch (48 loads in flight) retained from round 4.
// NO occupancy attribute: rounds 1/3 proved any waves_per_eu/launch_bounds(,2) hint
// triggers a 128-VGPR cap -> 200-380 MB scratch spill.
__global__ __launch_bounds__(256, 1) void mla_decode(
    const float* __restrict__ qn, const float* __restrict__ qr,
    const float* __restrict__ kn, const float* __restrict__ kr,
    const int* __restrict__ bt, float* __restrict__ out)
{
    // LDS: [0,40960): V^T per wave (128 dims x 40 shorts); [40960,51200): P per wave (32 x 40 shorts)
    // combine phase reuses [0, 33280) as two fp32 slots of 4160 floats each
    __shared__ __align__(16) char smem[51200];

    const int tid = threadIdx.x;
    const int w   = tid >> 6;
    const int l   = tid & 63;
    const int b   = blockIdx.x;
    const int s   = (b & 7) | ((b >> 5) << 3);   // bijective: all 4 h of seq s on XCD s%8
    const int h   = (b >> 3) & 3;
    const int l15 = l & 15;
    const int l4  = l >> 4;

    short* Vt = (short*)smem + w * (DN * VT_STRIDE);
    short* Pl = (short*)(smem + 4 * DN * VT_STRIDE * 2) + w * (32 * P_STRIDE);

    // ---- Q fragments (B-layout, resident all kernel): qf[ks][nt]
    s16x8 qf[6][2];
    #pragma unroll
    for (int nt = 0; nt < 2; ++nt) {
        int qcol = l15 + 16 * nt;
        int qpos = qcol >> 3, g = qcol & 7;
        const float* qnb = qn + ((size_t)((s*QL + qpos)*NH + h*GRP + g)) * DN + l4*8;
        const float* qrb = qr + ((size_t)((s*QL + qpos)*NH + h*GRP + g)) * DR + l4*8;
        #pragma unroll
        for (int ks = 0; ks < 4; ++ks) {
            f32x4 a = *(const f32x4*)(qnb + 32*ks);
            f32x4 bq = *(const f32x4*)(qnb + 32*ks + 4);
            qf[ks][nt] = cvt8(a, bq);
        }
        #pragma unroll
        for (int ks = 0; ks < 2; ++ks) {
            f32x4 a = *(const f32x4*)(qrb + 32*ks);
            f32x4 bq = *(const f32x4*)(qrb + 32*ks + 4);
            qf[4+ks][nt] = cvt8(a, bq);
        }
    }

    const float scale = 0.07216878364870322f;  // 1/sqrt(192)

    f32x4 of[8][2];                    // O^T accum: row dim=16mt+(l>>4)*4+r, col qcol=(l&15)+16nt
    #pragma unroll
    for (int mt = 0; mt < 8; ++mt)
        #pragma unroll
        for (int nt = 0; nt < 2; ++nt) of[mt][nt] = f32x4{0.f, 0.f, 0.f, 0.f};
    float m2[2] = {-INFINITY, -INFINITY};
    float l2[2] = {0.f, 0.f};

    const int btbase = s * (KL / BS) + w * 32;
    // all 32 block ids for this wave, lane-indexed (lanes 32-63 duplicate)
    int btreg = bt[btbase + (l & 31)];

    // ---- 32-lane bitonic sort, ascending in lanes 0..31 (lanes 32..63 mirror ops;
    // all shfl_xor partners stay within each 32-half since j<32). Attention output is
    // invariant to token processing order, so sorted order is free.
    #pragma unroll
    for (int k = 2; k <= 32; k <<= 1) {
        #pragma unroll
        for (int j = k >> 1; j >= 1; j >>= 1) {
            int p = __shfl_xor(btreg, j, 64);
            bool up = ((l & k) == 0);
            bool keepmin = (((l & j) == 0) == up);
            int mn = btreg < p ? btreg : p;
            int mx = btreg < p ? p : btreg;
            btreg = keepmin ? mn : mx;
        }
    }

    // issue the 12 float4 loads (one 16-token kv-block: 128 nope + 64 rope dims) for block id blkv
    auto loadK = [&](int blkv, f32x4* dst) {
        int blk = __builtin_amdgcn_readfirstlane(blkv);   // scalar base -> SALU addressing
        const float* knb = kn + ((size_t)(blk*BS + l15)*KVH + h) * DN + l4*8;
        const float* krb = kr + ((size_t)(blk*BS + l15)*KVH + h) * DR + l4*8;
        #pragma unroll
        for (int ks = 0; ks < 4; ++ks) {
            dst[2*ks]   = *(const f32x4*)(knb + 32*ks);
            dst[2*ks+1] = *(const f32x4*)(knb + 32*ks + 4);
        }
        #pragma unroll
        for (int ks = 0; ks < 2; ++ks) {
            dst[8+2*ks]   = *(const f32x4*)(krb + 32*ks);
            dst[8+2*ks+1] = *(const f32x4*)(krb + 32*ks + 4);
        }
    };

    f32x4 buf0[12], buf1[12], buf2[12], buf3[12];
    loadK(__shfl(btreg, 0, 64), buf0);
    loadK(__shfl(btreg, 1, 64), buf1);
    loadK(__shfl(btreg, 2, 64), buf2);
    loadK(__shfl(btreg, 3, 64), buf3);

    // one chunk = 32 tokens = tiles t, t+1 in buffers A, B; reloads tiles t+4, t+5 into A, B
    auto chunk = [&](f32x4* A, f32x4* B, int t, bool pf) {
        f32x4 sf[2][2];
        #pragma unroll
        for (int mt = 0; mt < 2; ++mt)
            #pragma unroll
            for (int nt = 0; nt < 2; ++nt) sf[mt][nt] = f32x4{0.f, 0.f, 0.f, 0.f};

        auto qkstep = [&](const f32x4* ld, int mt) {
            s16x8 af[6];
            #pragma unroll
            for (int ks = 0; ks < 6; ++ks) af[ks] = cvt8(ld[2*ks], ld[2*ks+1]);
            // stage V^T (nope dims only); same-wave lgkm ordering, no barrier
            #pragma unroll
            for (int ks = 0; ks < 4; ++ks) {
                int dbase = l4*8 + 32*ks;
                #pragma unroll
                for (int j = 0; j < 8; ++j)
                    Vt[(dbase + j) * VT_STRIDE + 16*mt + l15] = af[ks][j];
            }
            // S^T = K * Q^T  (A = K tile: m=token, B = Q: n=qcol)
            #pragma unroll
            for (int ks = 0; ks < 6; ++ks) {
                sf[mt][0] = __builtin_amdgcn_mfma_f32_16x16x32_bf16(af[ks], qf[ks][0], sf[mt][0], 0, 0, 0);
                sf[mt][1] = __builtin_amdgcn_mfma_f32_16x16x32_bf16(af[ks], qf[ks][1], sf[mt][1], 0, 0, 0);
            }
        };

        qkstep(A, 0);
        if (pf) loadK(__shfl(btreg, t + 4, 64), A);
        qkstep(B, 1);
        if (pf) loadK(__shfl(btreg, t + 5, 64), B);

        // ---- online softmax over this chunk's 32 tokens
        float cmax[2] = {-INFINITY, -INFINITY};
        #pragma unroll
        for (int mt = 0; mt < 2; ++mt)
            #pragma unroll
            for (int nt = 0; nt < 2; ++nt)
                #pragma unroll
                for (int r = 0; r < 4; ++r) cmax[nt] = fmaxf(cmax[nt], sf[mt][nt][r]);
        #pragma unroll
        for (int nt = 0; nt < 2; ++nt) {
            cmax[nt] = fmaxf(cmax[nt], __shfl_xor(cmax[nt], 16, 64));
            cmax[nt] = fmaxf(cmax[nt], __shfl_xor(cmax[nt], 32, 64));
        }
        float alpha[2], psum[2];
        #pragma unroll
        for (int nt = 0; nt < 2; ++nt) {
            float mn = fmaxf(m2[nt], cmax[nt] * scale);
            alpha[nt] = __expf(m2[nt] - mn);
            m2[nt] = mn;
            psum[nt] = 0.f;
        }
        float p[2][2][4];
        #pragma unroll
        for (int mt = 0; mt < 2; ++mt)
            #pragma unroll
            for (int nt = 0; nt < 2; ++nt)
                #pragma unroll
                for (int r = 0; r < 4; ++r) {
                    float e = __expf(sf[mt][nt][r] * scale - m2[nt]);
                    p[mt][nt][r] = e; psum[nt] += e;
                }
        #pragma unroll
        for (int nt = 0; nt < 2; ++nt) {
            psum[nt] += __shfl_xor(psum[nt], 16, 64);
            psum[nt] += __shfl_xor(psum[nt], 32, 64);
            l2[nt] = l2[nt] * alpha[nt] + psum[nt];
        }
        #pragma unroll
        for (int mt = 0; mt < 8; ++mt)
            #pragma unroll
            for (int nt = 0; nt < 2; ++nt) {
                of[mt][nt][0] *= alpha[nt]; of[mt][nt][1] *= alpha[nt];
                of[mt][nt][2] *= alpha[nt]; of[mt][nt][3] *= alpha[nt];
            }

        // ---- P round-trip: C-layout -> b64 write; B-frag b128 read
        #pragma unroll
        for (int mt = 0; mt < 2; ++mt)
            #pragma unroll
            for (int nt = 0; nt < 2; ++nt) {
                unsigned lo = (unsigned short)f2bf(p[mt][nt][0]) | ((unsigned)(unsigned short)f2bf(p[mt][nt][1]) << 16);
                unsigned hi = (unsigned short)f2bf(p[mt][nt][2]) | ((unsigned)(unsigned short)f2bf(p[mt][nt][3]) << 16);
                unsigned long long v = (unsigned long long)lo | ((unsigned long long)hi << 32);
                *(unsigned long long*)(Pl + (l15 + 16*nt) * P_STRIDE + 16*mt + l4*4) = v;
            }
        s16x8 pf2[2];
        #pragma unroll
        for (int nt = 0; nt < 2; ++nt)
            pf2[nt] = *(const s16x8*)(Pl + (l15 + 16*nt) * P_STRIDE + l4*8);

        // ---- O^T += V^T * P^T
        #pragma unroll
        for (int mt = 0; mt < 8; ++mt) {
            s16x8 vf = *(const s16x8*)(Vt + (l15 + 16*mt) * VT_STRIDE + l4*8);
            of[mt][0] = __builtin_amdgcn_mfma_f32_16x16x32_bf16(vf, pf2[0], of[mt][0], 0, 0, 0);
            of[mt][1] = __builtin_amdgcn_mfma_f32_16x16x32_bf16(vf, pf2[1], of[mt][1], 0, 0, 0);
        }
    };

    #pragma unroll 1
    for (int cp = 0; cp < 8; ++cp) {   // 8 chunk-pairs x 64 tokens per wave
        chunk(buf0, buf1, 4*cp,     cp < 7);
        chunk(buf2, buf3, 4*cp + 2, cp < 7);
    }

    // ---- cross-wave flash combine (tree, 2 fp32 LDS slots, reuses main-loop LDS)
    auto dump = [&](int slot) {
        float* sp = (float*)smem + slot * 4160;
        #pragma unroll
        for (int mt = 0; mt < 8; ++mt)
            #pragma unroll
            for (int nt = 0; nt < 2; ++nt)
                #pragma unroll
                for (int r = 0; r < 4; ++r)
                    sp[(16*mt + l4*4 + r) * 32 + l15 + 16*nt] = of[mt][nt][r];
        if (l4 == 0) {
            sp[4096 + l15]      = m2[0]; sp[4096 + 16 + l15] = m2[1];
            sp[4128 + l15]      = l2[0]; sp[4128 + 16 + l15] = l2[1];
        }
    };
    auto merge = [&](int slot) {
        float* sp = (float*)smem + slot * 4160;
        float as[2], ao[2];
        #pragma unroll
        for (int nt = 0; nt < 2; ++nt) {
            int qcol = l15 + 16*nt;
            float mo = sp[4096 + qcol];
            float lo = sp[4128 + qcol];
            float mn = fmaxf(m2[nt], mo);
            as[nt] = __expf(m2[nt] - mn);
            ao[nt] = __expf(mo - mn);
            l2[nt] = l2[nt] * as[nt] + lo * ao[nt];
            m2[nt] = mn;
        }
        #pragma unroll
        for (int mt = 0; mt < 8; ++mt)
            #pragma unroll
            for (int nt = 0; nt < 2; ++nt)
                #pragma unroll
                for (int r = 0; r < 4; ++r)
                    of[mt][nt][r] = of[mt][nt][r] * as[nt]
                                  + sp[(16*mt + l4*4 + r) * 32 + l15 + 16*nt] * ao[nt];
    };

    __syncthreads();
    if (w & 1) dump(w >> 1);          // waves 1,3 -> slots 0,1
    __syncthreads();
    if (!(w & 1)) merge(w >> 1);      // waves 0,2 merge partners
    __syncthreads();
    if (w == 2) dump(0);
    __syncthreads();
    if (w == 0) {
        merge(0);
        float inv[2] = {1.f / l2[0], 1.f / l2[1]};
        #pragma unroll
        for (int nt = 0; nt < 2; ++nt) {
            int qcol = l15 + 16*nt;
            int qpos = qcol >> 3, g = qcol & 7;
            float* ob = out + ((size_t)((s*QL + qpos)*NH + h*GRP + g)) * DN;
            #pragma unroll
            for (int mt = 0; mt < 8; ++mt) {
                f32x4 v;
                v[0] = of[mt][nt][0] * inv[nt]; v[1] = of[mt][nt][1] * inv[nt];
                v[2] = of[mt][nt][2] * inv[nt]; v[3] = of[mt][nt][3] * inv[nt];
                *(f32x4*)(ob + 16*mt + l4*4) = v;
            }
        }
    }
}

extern "C" void kernel_launch(void* const* d_in, const int* in_sizes, int n_in,
                              void* d_out, int out_size, void* d_ws, size_t ws_size,
                              hipStream_t stream) {
    (void)in_sizes; (void)n_in; (void)out_size; (void)d_ws; (void)ws_size;
    const float* qn = (const float*)d_in[0];
    const float* qr = (const float*)d_in[1];
    const float* kn = (const float*)d_in[2];
    const float* kr = (const float*)d_in[3];
    const int*   bt = (const int*)d_in[4];
    float* out = (float*)d_out;
    mla_decode<<<SEQS * KVH, 256, 0, stream>>>(qn, qr, kn, kr, bt, out);
}